// Round 1
// 282.369 us; speedup vs baseline: 1.0186x; 1.0186x over previous
//
#include <hip/hip_runtime.h>
#include <hip/hip_fp16.h>

#define NPTS 100000
#define NB 500
#define KNN 100
#define KPN 15
#define C1 128
#define C2 1024
#define C3 512
#define C4 256

typedef _Float16 half8 __attribute__((ext_vector_type(8)));
typedef float f32x4 __attribute__((ext_vector_type(4)));

// ------------------------------------------------- prep: gather + converts
// Fused gather (sel/normal) + weight conversions: one launch instead of two.
__global__ __launch_bounds__(256) void prep_kernel(
    const float* __restrict__ pts, const float* __restrict__ normal,
    const int* __restrict__ index, const float* __restrict__ w1,
    const float* __restrict__ kpw, float* __restrict__ sel,
    float* __restrict__ out2, __half* __restrict__ wh,
    __half* __restrict__ kpwT_hi, __half* __restrict__ kpwT_lo) {
  int i = blockIdx.x * 256 + threadIdx.x;
  if (i < NB) {
    int ix = index[i];
    sel[i * 3 + 0] = pts[3 * ix + 0];
    sel[i * 3 + 1] = pts[3 * ix + 1];
    sel[i * 3 + 2] = pts[3 * ix + 2];
    out2[i * 3 + 0] = normal[3 * ix + 0];
    out2[i * 3 + 1] = normal[3 * ix + 1];
    out2[i * 3 + 2] = normal[3 * ix + 2];
  }
  if (i < C2 * C1) wh[i] = __float2half(w1[i]);
  if (i < 128 * 64) {
    int o = i >> 6, j = i & 63;
    float v = (j < 45) ? kpw[j * 128 + o] : 0.f;
    __half hi = __float2half_rn(v);
    kpwT_hi[i] = hi;
    kpwT_lo[i] = __float2half_rn(v - __half2float(hi));
  }
}

// ---------------------------------------------------------------- kNN v4
// Q=2 queries per block: each loaded point feeds two linf chains, halving
// L2 traffic and per-point overhead per pair. 1024 threads (16 waves),
// 250 blocks (~1/CU). Histogram scan + collect + exact rank-select on the
// boundary bin, per query; rare refinement passes handled per-query via
// an active mask.
#define KT 1024

__device__ __forceinline__ unsigned linf_bits(float px, float py, float pz,
                                              float sx, float sy, float sz) {
  float dx = fabsf(px - sx), dy = fabsf(py - sy), dz = fabsf(pz - sz);
  return __float_as_uint(fmaxf(fmaxf(dx, dy), dz));
}

__global__ __launch_bounds__(KT) void knn_kernel(
    const float* __restrict__ pts, const float* __restrict__ sel,
    int* __restrict__ nbr) {
  const int b0 = blockIdx.x * 2;
  const int tid = threadIdx.x;
  __shared__ unsigned hist[2][4096];
  __shared__ unsigned chunksum[2][256];
  __shared__ unsigned s_prefix[2];
  __shared__ int s_kneed[2], s_cnt[2];
  __shared__ int s_direct[2], s_cnt2[2];
  __shared__ unsigned cand_bits[2][1024];
  __shared__ int cand_idx[2][1024];

  const float sx0 = sel[b0 * 3 + 0], sy0 = sel[b0 * 3 + 1],
              sz0 = sel[b0 * 3 + 2];
  const float sx1 = sel[b0 * 3 + 3], sy1 = sel[b0 * 3 + 4],
              sz1 = sel[b0 * 3 + 5];
  const float4* base4 = (const float4*)pts;

  for (int j = tid; j < 2 * 4096; j += KT) ((unsigned*)hist)[j] = 0;
  __syncthreads();

  // ---------------- pass 1: 12-bit histograms, both queries
  {
    float4 c[6], n[6];
    int i0 = tid * 8;
#pragma unroll
    for (int j = 0; j < 6; ++j) c[j] = base4[(i0 * 3) / 4 + j];
    for (int it = 0; it < 12; ++it) {
      if (it + 1 < 12) {
        int i1 = (it + 1) * 8192 + tid * 8;
#pragma unroll
        for (int j = 0; j < 6; ++j) n[j] = base4[(i1 * 3) / 4 + j];
      }
      float px[8], py[8], pz[8];
      px[0] = c[0].x; py[0] = c[0].y; pz[0] = c[0].z;
      px[1] = c[0].w; py[1] = c[1].x; pz[1] = c[1].y;
      px[2] = c[1].z; py[2] = c[1].w; pz[2] = c[2].x;
      px[3] = c[2].y; py[3] = c[2].z; pz[3] = c[2].w;
      px[4] = c[3].x; py[4] = c[3].y; pz[4] = c[3].z;
      px[5] = c[3].w; py[5] = c[4].x; pz[5] = c[4].y;
      px[6] = c[4].z; py[6] = c[4].w; pz[6] = c[5].x;
      px[7] = c[5].y; py[7] = c[5].z; pz[7] = c[5].w;
#pragma unroll
      for (int j = 0; j < 8; ++j) {
        unsigned u0 = linf_bits(px[j], py[j], pz[j], sx0, sy0, sz0);
        unsigned u1 = linf_bits(px[j], py[j], pz[j], sx1, sy1, sz1);
        atomicAdd(&hist[0][u0 >> 19], 1u);
        atomicAdd(&hist[1][u1 >> 19], 1u);
      }
#pragma unroll
      for (int j = 0; j < 6; ++j) c[j] = n[j];
    }
    for (int i = 98304 + tid; i < NPTS; i += KT) {
      float x = pts[3 * i], y = pts[3 * i + 1], z = pts[3 * i + 2];
      atomicAdd(&hist[0][linf_bits(x, y, z, sx0, sy0, sz0) >> 19], 1u);
      atomicAdd(&hist[1][linf_bits(x, y, z, sx1, sy1, sz1) >> 19], 1u);
    }
  }

  // ---------------- boundary-bin selection per query (+rare refinement)
  unsigned shiftq[2] = {19u, 19u};
  unsigned prefixq[2] = {0u, 0u};
  unsigned pendw[2] = {0u, 0u};
  int kneedq[2] = {KNN, KNN};
  int activeq = 3;
  for (int pass = 0;; ++pass) {
    __syncthreads();
    if (tid < 512) {
      int q = tid >> 8;
      if (activeq & (1 << q)) {
        int ch = tid & 255;
        unsigned csum = 0;
        for (int j = 0; j < 16; ++j) csum += hist[q][ch * 16 + j];
        chunksum[q][ch] = csum;
      }
    }
    __syncthreads();
    if (tid < 2 && (activeq & (1 << tid))) {
      const int q = tid;
      unsigned need = (unsigned)kneedq[q];
      unsigned cum = 0;
      int chunk = 0;
      while (chunk < 255 && cum + chunksum[q][chunk] < need) {
        cum += chunksum[q][chunk];
        ++chunk;
      }
      int bin = chunk * 16;
      while (cum + hist[q][bin] < need) {
        cum += hist[q][bin];
        ++bin;
      }
      s_kneed[q] = (int)(need - cum);
      s_prefix[q] = (unsigned)bin;
      s_cnt[q] = (int)hist[q][bin];
    }
    __syncthreads();
    int newactive = 0;
#pragma unroll
    for (int q = 0; q < 2; ++q) {
      if (!(activeq & (1 << q))) continue;
      kneedq[q] = s_kneed[q];
      prefixq[q] = (pass == 0) ? s_prefix[q]
                               : ((prefixq[q] << pendw[q]) | s_prefix[q]);
      if (s_cnt[q] > 1024 && shiftq[q] != 0u) newactive |= (1 << q);
    }
    if (!newactive) break;
    for (int q = 0; q < 2; ++q)
      if (newactive & (1 << q))
        for (int j = tid; j < 4096; j += KT) hist[q][j] = 0;
    unsigned fs0 = shiftq[0], fs1 = shiftq[1];
    unsigned ns0 = (fs0 == 19u) ? 7u : 0u;
    unsigned ns1 = (fs1 == 19u) ? 7u : 0u;
#pragma unroll
    for (int q = 0; q < 2; ++q)
      if (newactive & (1 << q)) pendw[q] = (shiftq[q] == 19u) ? 12u : 7u;
    __syncthreads();
    for (int i = tid; i < NPTS; i += KT) {
      float x = pts[3 * i], y = pts[3 * i + 1], z = pts[3 * i + 2];
      if (newactive & 1) {
        unsigned bits = linf_bits(x, y, z, sx0, sy0, sz0);
        if ((bits >> fs0) == prefixq[0]) {
          unsigned bin = (ns0 == 7u) ? ((bits >> 7) & 4095u) : (bits & 127u);
          atomicAdd(&hist[0][bin], 1u);
        }
      }
      if (newactive & 2) {
        unsigned bits = linf_bits(x, y, z, sx1, sy1, sz1);
        if ((bits >> fs1) == prefixq[1]) {
          unsigned bin = (ns1 == 7u) ? ((bits >> 7) & 4095u) : (bits & 127u);
          atomicAdd(&hist[1][bin], 1u);
        }
      }
    }
    if (newactive & 1) shiftq[0] = ns0;
    if (newactive & 2) shiftq[1] = ns1;
    activeq = newactive;
  }

  // ---------------- collect pass, both queries
  if (tid == 0) {
    s_direct[0] = 0;
    s_direct[1] = 0;
    s_cnt2[0] = 0;
    s_cnt2[1] = 0;
  }
  __syncthreads();
  const unsigned sh0 = shiftq[0], sh1 = shiftq[1];
  const unsigned pf0 = prefixq[0], pf1 = prefixq[1];
  {
    float4 c[6], n[6];
    int i0 = tid * 8;
#pragma unroll
    for (int j = 0; j < 6; ++j) c[j] = base4[(i0 * 3) / 4 + j];
    for (int it = 0; it < 12; ++it) {
      if (it + 1 < 12) {
        int i1 = (it + 1) * 8192 + tid * 8;
#pragma unroll
        for (int j = 0; j < 6; ++j) n[j] = base4[(i1 * 3) / 4 + j];
      }
      float px[8], py[8], pz[8];
      px[0] = c[0].x; py[0] = c[0].y; pz[0] = c[0].z;
      px[1] = c[0].w; py[1] = c[1].x; pz[1] = c[1].y;
      px[2] = c[1].z; py[2] = c[1].w; pz[2] = c[2].x;
      px[3] = c[2].y; py[3] = c[2].z; pz[3] = c[2].w;
      px[4] = c[3].x; py[4] = c[3].y; pz[4] = c[3].z;
      px[5] = c[3].w; py[5] = c[4].x; pz[5] = c[4].y;
      px[6] = c[4].z; py[6] = c[4].w; pz[6] = c[5].x;
      px[7] = c[5].y; py[7] = c[5].z; pz[7] = c[5].w;
      int ibase = it * 8192 + tid * 8;
#pragma unroll
      for (int j = 0; j < 8; ++j) {
        unsigned u0 = linf_bits(px[j], py[j], pz[j], sx0, sy0, sz0);
        unsigned v0 = u0 >> sh0;
        if (v0 < pf0) {
          int pos = atomicAdd(&s_direct[0], 1);
          nbr[b0 * KNN + pos] = ibase + j;
        } else if (v0 == pf0) {
          int e = atomicAdd(&s_cnt2[0], 1);
          if (e < 1024) {
            cand_bits[0][e] = u0;
            cand_idx[0][e] = ibase + j;
          }
        }
        unsigned u1 = linf_bits(px[j], py[j], pz[j], sx1, sy1, sz1);
        unsigned v1 = u1 >> sh1;
        if (v1 < pf1) {
          int pos = atomicAdd(&s_direct[1], 1);
          nbr[(b0 + 1) * KNN + pos] = ibase + j;
        } else if (v1 == pf1) {
          int e = atomicAdd(&s_cnt2[1], 1);
          if (e < 1024) {
            cand_bits[1][e] = u1;
            cand_idx[1][e] = ibase + j;
          }
        }
      }
#pragma unroll
      for (int j = 0; j < 6; ++j) c[j] = n[j];
    }
    for (int i = 98304 + tid; i < NPTS; i += KT) {
      float x = pts[3 * i], y = pts[3 * i + 1], z = pts[3 * i + 2];
      unsigned u0 = linf_bits(x, y, z, sx0, sy0, sz0);
      unsigned v0 = u0 >> sh0;
      if (v0 < pf0) {
        int pos = atomicAdd(&s_direct[0], 1);
        nbr[b0 * KNN + pos] = i;
      } else if (v0 == pf0) {
        int e = atomicAdd(&s_cnt2[0], 1);
        if (e < 1024) {
          cand_bits[0][e] = u0;
          cand_idx[0][e] = i;
        }
      }
      unsigned u1 = linf_bits(x, y, z, sx1, sy1, sz1);
      unsigned v1 = u1 >> sh1;
      if (v1 < pf1) {
        int pos = atomicAdd(&s_direct[1], 1);
        nbr[(b0 + 1) * KNN + pos] = i;
      } else if (v1 == pf1) {
        int e = atomicAdd(&s_cnt2[1], 1);
        if (e < 1024) {
          cand_bits[1][e] = u1;
          cand_idx[1][e] = i;
        }
      }
    }
  }
  __syncthreads();

#pragma unroll
  for (int q = 0; q < 2; ++q) {
    int m = s_cnt2[q] < 1024 ? s_cnt2[q] : 1024;
    int base = s_direct[q];
    for (int c2 = tid; c2 < m; c2 += KT) {
      unsigned bc = cand_bits[q][c2];
      int ic = cand_idx[q][c2];
      int rank = 0;
      for (int j = 0; j < m; ++j) {
        unsigned bj = cand_bits[q][j];
        rank += (bj < bc || (bj == bc && cand_idx[q][j] < ic)) ? 1 : 0;
      }
      if (rank < kneedq[q]) nbr[(b0 + q) * KNN + base + rank] = ic;
    }
  }
}

// ------------------------------------------------- KPConv (f16 MFMA, hi/lo)
// h[100x128] = relu(A[100x64] x kpwT^T); A[k][p*3+c] = rel[k][c]*gauss(k,p).
// A and B both hi/lo split; acc = Ahi*Bhi + Ahi*Blo + Alo*Bhi (fp32 acc).
__global__ __launch_bounds__(256) void kpconv_mfma_kernel(
    const float* __restrict__ pts, const float* __restrict__ sel,
    const int* __restrict__ nbr, const float* __restrict__ kp_points,
    const __half* __restrict__ kpwT_hi, const __half* __restrict__ kpwT_lo,
    const float* __restrict__ kp_sigma, __half* __restrict__ h) {
  const int b = blockIdx.x;
  const int tid = threadIdx.x;
  const int wave = tid >> 6, lane = tid & 63;
  const int lr = lane & 15, quad = lane >> 4;
  __shared__ __half As_hi[112 * 72];  // +8 pad
  __shared__ __half As_lo[112 * 72];
  __shared__ __half Bs_hi[128 * 72];
  __shared__ __half Bs_lo[128 * 72];
  __shared__ float rel[100][4];
  __shared__ float kpp[48];

  for (int i = tid; i < 128 * 8; i += 256) {
    int row = i >> 3, seg = i & 7;
    *(float4*)&Bs_hi[row * 72 + seg * 8] =
        *(const float4*)&kpwT_hi[row * 64 + seg * 8];
    *(float4*)&Bs_lo[row * 72 + seg * 8] =
        *(const float4*)&kpwT_lo[row * 64 + seg * 8];
  }
  {
    float4 z = make_float4(0.f, 0.f, 0.f, 0.f);
    for (int i = tid; i < 112 * 8; i += 256) {
      int row = i >> 3, seg = i & 7;
      *(float4*)&As_hi[row * 72 + seg * 8] = z;
      *(float4*)&As_lo[row * 72 + seg * 8] = z;
    }
  }
  if (tid < 45) kpp[tid] = kp_points[tid];
  if (tid < 100) {
    int idx = nbr[b * KNN + tid];
    rel[tid][0] = pts[3 * idx + 0] - sel[b * 3 + 0];
    rel[tid][1] = pts[3 * idx + 1] - sel[b * 3 + 1];
    rel[tid][2] = pts[3 * idx + 2] - sel[b * 3 + 2];
  }
  __syncthreads();

  const float sg = kp_sigma[0];
  const float inv2s2 = -0.5f / (sg * sg);
  for (int i = tid; i < 100 * KPN; i += 256) {
    int k = i / KPN, p = i - k * KPN;
    float rx = rel[k][0] - kpp[p * 3 + 0];
    float ry = rel[k][1] - kpp[p * 3 + 1];
    float rz = rel[k][2] - kpp[p * 3 + 2];
    float w = expf(inv2s2 * (rx * rx + ry * ry + rz * rz));
#pragma unroll
    for (int c = 0; c < 3; ++c) {
      float a = rel[k][c] * w;
      __half hi = __float2half_rn(a);
      As_hi[k * 72 + p * 3 + c] = hi;
      As_lo[k * 72 + p * 3 + c] = __float2half_rn(a - __half2float(hi));
    }
  }
  __syncthreads();

  f32x4 acc[2][7];
#pragma unroll
  for (int t = 0; t < 2; ++t)
#pragma unroll
    for (int m = 0; m < 7; ++m) acc[t][m] = (f32x4)(0.f);

#pragma unroll
  for (int s = 0; s < 2; ++s) {
    half8 bhi[2], blo[2];
#pragma unroll
    for (int t = 0; t < 2; ++t) {
      int boff = ((wave * 2 + t) * 16 + lr) * 72 + s * 32 + quad * 8;
      bhi[t] = *(const half8*)&Bs_hi[boff];
      blo[t] = *(const half8*)&Bs_lo[boff];
    }
#pragma unroll
    for (int m = 0; m < 7; ++m) {
      int aoff = (m * 16 + lr) * 72 + s * 32 + quad * 8;
      half8 ahi = *(const half8*)&As_hi[aoff];
      half8 alo = *(const half8*)&As_lo[aoff];
#pragma unroll
      for (int t = 0; t < 2; ++t) {
        acc[t][m] = __builtin_amdgcn_mfma_f32_16x16x32_f16(ahi, bhi[t],
                                                           acc[t][m], 0, 0, 0);
        acc[t][m] = __builtin_amdgcn_mfma_f32_16x16x32_f16(ahi, blo[t],
                                                           acc[t][m], 0, 0, 0);
        acc[t][m] = __builtin_amdgcn_mfma_f32_16x16x32_f16(alo, bhi[t],
                                                           acc[t][m], 0, 0, 0);
      }
    }
  }

#pragma unroll
  for (int t = 0; t < 2; ++t) {
    int col = (wave * 2 + t) * 16 + lr;
#pragma unroll
    for (int m = 0; m < 7; ++m)
#pragma unroll
      for (int r = 0; r < 4; ++r) {
        int row = m * 16 + quad * 4 + r;
        if (row < 100)
          h[(b * KNN + row) * 128 + col] =
              __float2half_rn(fmaxf(acc[t][m][r], 0.f));
      }
  }
}

// ------------------------------------------------------- conv1 (f16 MFMA)
__global__ __launch_bounds__(256) void conv1_mfma_kernel(
    const __half* __restrict__ h16, const __half* __restrict__ wh,
    const float* __restrict__ bias, float* __restrict__ featmax,
    float* __restrict__ featmin, float* __restrict__ bnsum,
    float* __restrict__ bnsq) {
  const int b = blockIdx.y;
  const int n0 = blockIdx.x * 128;
  const int tid = threadIdx.x;
  const int wave = tid >> 6, lane = tid & 63;
  const int lr = lane & 15, quad = lane >> 4;
  __shared__ __half Hs[112 * 136];
  __shared__ __half Ws[128 * 136];

  for (int i = tid; i < 112 * 16; i += 256) {
    int row = i >> 4, seg = i & 15;
    float4 v = make_float4(0.f, 0.f, 0.f, 0.f);
    if (row < 100) v = *(const float4*)&h16[(b * 100 + row) * 128 + seg * 8];
    *(float4*)&Hs[row * 136 + seg * 8] = v;
  }
  for (int i = tid; i < 128 * 16; i += 256) {
    int row = i >> 4, seg = i & 15;
    *(float4*)&Ws[row * 136 + seg * 8] =
        *(const float4*)&wh[(n0 + row) * 128 + seg * 8];
  }
  __syncthreads();

  f32x4 acc[2][7];
#pragma unroll
  for (int t = 0; t < 2; ++t)
#pragma unroll
    for (int m = 0; m < 7; ++m) acc[t][m] = (f32x4)(0.f);

#pragma unroll
  for (int s = 0; s < 4; ++s) {
    half8 bfrag[2];
#pragma unroll
    for (int t = 0; t < 2; ++t)
      bfrag[t] =
          *(const half8*)&Ws[((wave * 2 + t) * 16 + lr) * 136 + s * 32 + quad * 8];
#pragma unroll
    for (int m = 0; m < 7; ++m) {
      half8 afrag = *(const half8*)&Hs[(m * 16 + lr) * 136 + s * 32 + quad * 8];
      acc[0][m] =
          __builtin_amdgcn_mfma_f32_16x16x32_f16(afrag, bfrag[0], acc[0][m], 0, 0, 0);
      acc[1][m] =
          __builtin_amdgcn_mfma_f32_16x16x32_f16(afrag, bfrag[1], acc[1][m], 0, 0, 0);
    }
  }

#pragma unroll
  for (int t = 0; t < 2; ++t) {
    int col = n0 + (wave * 2 + t) * 16 + lr;
    float bv = bias[col];
    float pmax = -1e30f, pmin = 1e30f, psum = 0.f, psq = 0.f;
#pragma unroll
    for (int m = 0; m < 7; ++m)
#pragma unroll
      for (int r = 0; r < 4; ++r) {
        int row = m * 16 + quad * 4 + r;
        if (row < 100) {
          float y = fmaxf(acc[t][m][r] + bv, 0.f);
          pmax = fmaxf(pmax, y);
          pmin = fminf(pmin, y);
          psum += y;
          psq += y * y;
        }
      }
    pmax = fmaxf(pmax, __shfl_xor(pmax, 16));
    pmax = fmaxf(pmax, __shfl_xor(pmax, 32));
    pmin = fminf(pmin, __shfl_xor(pmin, 16));
    pmin = fminf(pmin, __shfl_xor(pmin, 32));
    psum += __shfl_xor(psum, 16);
    psum += __shfl_xor(psum, 32);
    psq += __shfl_xor(psq, 16);
    psq += __shfl_xor(psq, 32);
    if (quad == 0) {
      featmax[b * C2 + col] = pmax;
      featmin[b * C2 + col] = pmin;
      atomicAdd(&bnsum[col], psum);
      atomicAdd(&bnsq[col], psq);
    }
  }
}

// ------------------------------------------------------- BN1 + max finalize
__global__ __launch_bounds__(256) void bn1max_kernel(
    const float* __restrict__ featmax, const float* __restrict__ featmin,
    const float* __restrict__ bnsum, const float* __restrict__ bnsq,
    const float* __restrict__ g, const float* __restrict__ bb,
    float* __restrict__ feat1) {
  int idx = blockIdx.x * 256 + threadIdx.x;
  if (idx >= NB * C2) return;
  int o = idx & (C2 - 1);
  const float invn = 1.f / (float)(NB * KNN);
  float m = bnsum[o] * invn;
  float v = bnsq[o] * invn - m * m;
  float a = g[o] / sqrtf(v + 1e-5f);
  float x = (a >= 0.f) ? featmax[idx] : featmin[idx];  // max of monotone map
  feat1[idx] = (x - m) * a + bb[o];
}

// ---------------------------------------------------------------- fc + stats
template <int KDIM>
__global__ __launch_bounds__(256) void fc_relu_stats_kernel(
    const float* __restrict__ x,  // [500][KDIM]
    const float* __restrict__ w,  // [N][KDIM]
    const float* __restrict__ bias, float* __restrict__ yraw,
    float* __restrict__ s, float* __restrict__ sq, int ncols) {
  const int r0 = blockIdx.x * 4;
  const int n0 = blockIdx.y * 64;
  const int tid = threadIdx.x;
  const int col = tid >> 2;  // 0..63
  const int row = tid & 3;
  __shared__ float xs[4][1028];
  __shared__ float ws[64][132];
  for (int f = tid; f < KDIM; f += 256) {  // KDIM float4's total
    int rr = f / (KDIM / 4), kq = (f % (KDIM / 4)) * 4;
    *(float4*)&xs[rr][kq] = *(const float4*)&x[(r0 + rr) * KDIM + kq];
  }
  float acc = 0.f;
  for (int kc = 0; kc < KDIM; kc += 128) {
    __syncthreads();
#pragma unroll
    for (int i = 0; i < 8; ++i) {
      int f = tid + i * 256;  // 0..2047
      int cr = f >> 5, kq = (f & 31) * 4;
      *(float4*)&ws[cr][kq] = *(const float4*)&w[(n0 + cr) * KDIM + kc + kq];
    }
    __syncthreads();
    for (int kk = 0; kk < 128; kk += 4) {
      float4 xv = *(float4*)&xs[row][kc + kk];
      float4 wv = *(float4*)&ws[col][kk];
      acc += xv.x * wv.x + xv.y * wv.y + xv.z * wv.z + xv.w * wv.w;
    }
  }
  float y = fmaxf(acc + bias[n0 + col], 0.f);
  yraw[(r0 + row) * ncols + n0 + col] = y;
  float ys = y, y2 = y * y;
  ys += __shfl_xor(ys, 1); y2 += __shfl_xor(y2, 1);
  ys += __shfl_xor(ys, 2); y2 += __shfl_xor(y2, 2);
  if (row == 0) {
    atomicAdd(&s[n0 + col], ys);
    atomicAdd(&sq[n0 + col], y2);
  }
}

// ---------------------------------------------------------------- BN finalize
__global__ __launch_bounds__(256) void bn_finalize_kernel(
    const float* __restrict__ yraw, const float* __restrict__ s,
    const float* __restrict__ sq, const float* __restrict__ g,
    const float* __restrict__ bb, float* __restrict__ out, int ncols) {
  int idx = blockIdx.x * 256 + threadIdx.x;
  if (idx >= NB * ncols) return;
  int o = idx & (ncols - 1);  // ncols is a power of two
  float m = s[o] * (1.f / (float)NB);
  float v = sq[o] * (1.f / (float)NB) - m * m;
  float a = g[o] / sqrtf(v + 1e-5f);
  out[idx] = (yraw[idx] - m) * a + bb[o];
}

// ---------------------------------------------------------------- fc3
__global__ __launch_bounds__(256) void fc3_kernel(
    const float* __restrict__ feat, const float* __restrict__ w,
    const float* __restrict__ bias, float* __restrict__ out) {
  int idx = blockIdx.x * 256 + threadIdx.x;
  if (idx >= NB * 3) return;
  int b = idx / 3, o = idx % 3;
  float acc = 0.f;
  for (int k = 0; k < C4; ++k) acc += feat[b * C4 + k] * w[o * C4 + k];
  out[idx] = acc + bias[o];
}

// ---------------------------------------------------------------- launch
extern "C" void kernel_launch(void* const* d_in, const int* in_sizes, int n_in,
                              void* d_out, int out_size, void* d_ws,
                              size_t ws_size, hipStream_t stream) {
  const float* pts = (const float*)d_in[0];
  const float* normal = (const float*)d_in[1];
  const float* kp_points = (const float*)d_in[2];
  const float* kp_weights = (const float*)d_in[3];
  const float* kp_sigma = (const float*)d_in[4];
  const float* conv1_w = (const float*)d_in[5];
  const float* conv1_b = (const float*)d_in[6];
  const float* bn1_g = (const float*)d_in[7];
  const float* bn1_b = (const float*)d_in[8];
  const float* fc1_w = (const float*)d_in[9];
  const float* fc1_b = (const float*)d_in[10];
  const float* bn4_g = (const float*)d_in[11];
  const float* bn4_b = (const float*)d_in[12];
  const float* fc2_w = (const float*)d_in[13];
  const float* fc2_b = (const float*)d_in[14];
  const float* bn5_g = (const float*)d_in[15];
  const float* bn5_b = (const float*)d_in[16];
  const float* fc3_w = (const float*)d_in[17];
  const float* fc3_b = (const float*)d_in[18];
  const int* index = (const int*)d_in[19];
  float* out = (float*)d_out;

  char* p = (char*)d_ws;
  auto carve = [&](size_t bytes) {
    void* r = (void*)p;
    p += (bytes + 255) & ~(size_t)255;
    return r;
  };
  float* sel = (float*)carve(NB * 3 * 4);
  int* nbr = (int*)carve(NB * KNN * 4);
  __half* h = (__half*)carve((size_t)NB * KNN * C1 * 2);
  __half* wh = (__half*)carve((size_t)C2 * C1 * 2);
  __half* kpwT_hi = (__half*)carve((size_t)128 * 64 * 2);
  __half* kpwT_lo = (__half*)carve((size_t)128 * 64 * 2);
  float* featmax = (float*)carve(NB * C2 * 4);
  float* featmin = (float*)carve(NB * C2 * 4);
  float* feat1 = (float*)carve(NB * C2 * 4);
  float* f2raw = (float*)carve(NB * C3 * 4);
  float* feat2 = (float*)carve(NB * C3 * 4);
  float* f3raw = (float*)carve(NB * C4 * 4);
  float* feat3 = (float*)carve(NB * C4 * 4);
  float* stats = (float*)carve((2 * C2 + 2 * C3 + 2 * C4) * 4);
  float* bnsum = stats;
  float* bnsq = stats + C2;
  float* s4 = stats + 2 * C2;
  float* sq4 = s4 + C3;
  float* s5 = sq4 + C3;
  float* sq5 = s5 + C4;

  hipMemsetAsync(stats, 0, (2 * C2 + 2 * C3 + 2 * C4) * 4, stream);

  prep_kernel<<<(C2 * C1 + 255) / 256, 256, 0, stream>>>(
      pts, normal, index, conv1_w, kp_weights, sel, out + NB * 3, wh, kpwT_hi,
      kpwT_lo);
  knn_kernel<<<NB / 2, KT, 0, stream>>>(pts, sel, nbr);
  kpconv_mfma_kernel<<<NB, 256, 0, stream>>>(pts, sel, nbr, kp_points, kpwT_hi,
                                             kpwT_lo, kp_sigma, h);
  conv1_mfma_kernel<<<dim3(8, NB), 256, 0, stream>>>(h, wh, conv1_b, featmax,
                                                     featmin, bnsum, bnsq);
  bn1max_kernel<<<(NB * C2 + 255) / 256, 256, 0, stream>>>(
      featmax, featmin, bnsum, bnsq, bn1_g, bn1_b, feat1);
  fc_relu_stats_kernel<C2><<<dim3(125, C3 / 64), 256, 0, stream>>>(
      feat1, fc1_w, fc1_b, f2raw, s4, sq4, C3);
  bn_finalize_kernel<<<(NB * C3 + 255) / 256, 256, 0, stream>>>(
      f2raw, s4, sq4, bn4_g, bn4_b, feat2, C3);
  fc_relu_stats_kernel<C3><<<dim3(125, C4 / 64), 256, 0, stream>>>(
      feat2, fc2_w, fc2_b, f3raw, s5, sq5, C4);
  bn_finalize_kernel<<<(NB * C4 + 255) / 256, 256, 0, stream>>>(
      f3raw, s5, sq5, bn5_g, bn5_b, feat3, C4);
  fc3_kernel<<<(NB * 3 + 255) / 256, 256, 0, stream>>>(feat3, fc3_w, fc3_b,
                                                       out);
}